// Round 1
// baseline (499.663 us; speedup 1.0000x reference)
//
#include <hip/hip_runtime.h>
#include <cstdint>
#include <cstddef>

// ---------------------------------------------------------------------------
// LSTM cell + 3-layer decoder, MI355X (gfx950)
// B=8192, H=1024, D_IN=1024, D1=512, D2=341(pad 384), A=512
// Strategy: f16 MFMA GEMMs (m97 structure: 128x128 tile, BK=32,
// global_load_lds width=16, mfma_f32_16x16x32_f16).
// Gates fused into one [8192,2048]x[4096,2048]^T GEMM with interleaved
// gate rows r=4*j+g so the pointwise kernel reads half4 per element.
// ---------------------------------------------------------------------------

typedef _Float16 half_t;
typedef _Float16 half8 __attribute__((ext_vector_type(8)));
typedef _Float16 half4v __attribute__((ext_vector_type(4)));
typedef float float4v __attribute__((ext_vector_type(4)));

#define GLD_LDS16(gptr, lptr)                                                  \
  __builtin_amdgcn_global_load_lds(                                            \
      (const __attribute__((address_space(1))) void*)(gptr),                   \
      (__attribute__((address_space(3))) void*)(lptr), 16, 0, 0)

__device__ __forceinline__ float sigmoidf_(float x) {
  return 1.0f / (1.0f + __expf(-x));
}

// ---------------------------------------------------------------------------
// GEMM: C[M,N] = A[M,K] @ Bw[N,K]^T + bias[N], optional tanh, f16 or f32 out.
// M multiple of 128 (grid.y), N multiple of 128 (grid.x), K multiple of 32.
// 256 threads = 4 waves in 2x2, each wave 64x64 via 4x4 MFMA 16x16 tiles.
// ---------------------------------------------------------------------------
template <int ACT_TANH, int HALF_OUT>
__global__ __launch_bounds__(256) void gemm_f16(const half_t* __restrict__ A,
                                                const half_t* __restrict__ Bw,
                                                const float* __restrict__ bias,
                                                void* __restrict__ Cp,
                                                int N, int K) {
  __shared__ alignas(16) half_t As[128 * 32];  // 8 KB
  __shared__ alignas(16) half_t Bs[128 * 32];  // 8 KB
  const int tid = threadIdx.x;
  const int lane = tid & 63;
  const int wave = tid >> 6;
  const size_t tile_m = (size_t)blockIdx.y * 128;
  const size_t tile_n = (size_t)blockIdx.x * 128;
  const int wm = (wave >> 1) * 64;
  const int wn = (wave & 1) * 64;

  // staging byte offsets within the 8KB tile: p = row*64 + colh*2
  const int p0 = tid * 16;         // [0, 4096)
  const int p1 = 4096 + tid * 16;  // [4096, 8192)
  const int r0 = p0 >> 6, c0 = (p0 & 63) >> 1;
  const int r1 = p1 >> 6, c1 = (p1 & 63) >> 1;

  const half_t* Ag0 = A + (tile_m + r0) * (size_t)K + c0;
  const half_t* Ag1 = A + (tile_m + r1) * (size_t)K + c1;
  const half_t* Bg0 = Bw + (tile_n + r0) * (size_t)K + c0;
  const half_t* Bg1 = Bw + (tile_n + r1) * (size_t)K + c1;

  float4v acc[4][4] = {};

  for (int k0 = 0; k0 < K; k0 += 32) {
    __syncthreads();
    GLD_LDS16(Ag0 + k0, (char*)As + p0);
    GLD_LDS16(Ag1 + k0, (char*)As + p1);
    GLD_LDS16(Bg0 + k0, (char*)Bs + p0);
    GLD_LDS16(Bg1 + k0, (char*)Bs + p1);
    __syncthreads();
    const int kh = (lane >> 4) * 8;  // k offset in halves
    half8 af[4], bf[4];
#pragma unroll
    for (int i = 0; i < 4; ++i)
      af[i] = *(const half8*)(As + (wm + i * 16 + (lane & 15)) * 32 + kh);
#pragma unroll
    for (int j = 0; j < 4; ++j)
      bf[j] = *(const half8*)(Bs + (wn + j * 16 + (lane & 15)) * 32 + kh);
#pragma unroll
    for (int i = 0; i < 4; ++i)
#pragma unroll
      for (int j = 0; j < 4; ++j)
        acc[i][j] =
            __builtin_amdgcn_mfma_f32_16x16x32_f16(af[i], bf[j], acc[i][j], 0, 0, 0);
  }

  // epilogue: C/D layout col=lane&15 (n), row=(lane>>4)*4+reg (m)  [m89-verified]
  const size_t mb = tile_m + wm + ((lane >> 4) << 2);
  const size_t nb = tile_n + wn + (lane & 15);
#pragma unroll
  for (int j = 0; j < 4; ++j) {
    const size_t n = nb + j * 16;
    const float bv = bias[n];
#pragma unroll
    for (int i = 0; i < 4; ++i) {
#pragma unroll
      for (int r = 0; r < 4; ++r) {
        float v = acc[i][j][r] + bv;
        if (ACT_TANH) v = tanhf(v);
        const size_t off = (mb + i * 16 + r) * (size_t)N + n;
        if (HALF_OUT)
          ((half_t*)Cp)[off] = (half_t)v;
        else
          ((float*)Cp)[off] = v;
      }
    }
  }
}

// ---------------------------------------------------------------------------
// pack x,h -> XH f16 [8192, 2048] (cols 0..1023 = x, 1024..2047 = h)
// ---------------------------------------------------------------------------
__global__ void pack_xh(const float* __restrict__ x, const float* __restrict__ h,
                        half_t* __restrict__ xh) {
  const size_t t = (size_t)blockIdx.x * blockDim.x + threadIdx.x;
  const size_t idx = t * 4;
  const size_t b = idx >> 11;
  const int col = (int)(idx & 2047);
  const float* src = (col < 1024) ? (x + b * 1024 + col) : (h + b * 1024 + (col - 1024));
  const float4v v = *(const float4v*)src;
  half4v o;
  o.x = (half_t)v.x; o.y = (half_t)v.y; o.z = (half_t)v.z; o.w = (half_t)v.w;
  *(half4v*)(xh + idx) = o;
}

// ---------------------------------------------------------------------------
// pack gate weights -> WALL f16 [4096, 2048]; row r=4j+g, g in {f,i,s,o};
// cols 0..1023 = W_gi[j,:], 1024..2047 = W_gh[j,:]
// ---------------------------------------------------------------------------
__global__ void pack_wall(const float* __restrict__ Wfi, const float* __restrict__ Wfh,
                          const float* __restrict__ Wii, const float* __restrict__ Wih,
                          const float* __restrict__ Wsi, const float* __restrict__ Wsh,
                          const float* __restrict__ Woi, const float* __restrict__ Woh,
                          half_t* __restrict__ wall) {
  const size_t t = (size_t)blockIdx.x * blockDim.x + threadIdx.x;
  const size_t idx = t * 4;
  const int r = (int)(idx >> 11);
  const int col = (int)(idx & 2047);
  const int g = r & 3;
  const size_t j = (size_t)(r >> 2);
  const float* Wi = (g == 0) ? Wfi : (g == 1) ? Wii : (g == 2) ? Wsi : Woi;
  const float* Wh = (g == 0) ? Wfh : (g == 1) ? Wih : (g == 2) ? Wsh : Woh;
  const float* src = (col < 1024) ? (Wi + j * 1024 + col) : (Wh + j * 1024 + (col - 1024));
  const float4v v = *(const float4v*)src;
  half4v o;
  o.x = (half_t)v.x; o.y = (half_t)v.y; o.z = (half_t)v.z; o.w = (half_t)v.w;
  *(half4v*)(wall + idx) = o;
}

__global__ void bias_all(const float* __restrict__ bfi, const float* __restrict__ bfh,
                         const float* __restrict__ bii, const float* __restrict__ bih,
                         const float* __restrict__ bsi, const float* __restrict__ bsh,
                         const float* __restrict__ boi, const float* __restrict__ boh,
                         float* __restrict__ ball) {
  const int r = blockIdx.x * blockDim.x + threadIdx.x;  // 4096
  const int g = r & 3, j = r >> 2;
  const float* bi = (g == 0) ? bfi : (g == 1) ? bii : (g == 2) ? bsi : boi;
  const float* bh = (g == 0) ? bfh : (g == 1) ? bih : (g == 2) ? bsh : boh;
  ball[r] = bi[j] + bh[j];
}

// f32 [srows,scols] -> f16 [*, dcols], zero-padded
__global__ void conv_pad(const float* __restrict__ src, half_t* __restrict__ dst,
                         int srows, int scols, int dcols, int total) {
  const int idx = blockIdx.x * blockDim.x + threadIdx.x;
  if (idx >= total) return;
  const int r = idx / dcols;
  const int c = idx - r * dcols;
  float v = (r < srows && c < scols) ? src[(size_t)r * scols + c] : 0.0f;
  dst[idx] = (half_t)v;
}

__global__ void pad_bias_k(const float* __restrict__ src, float* __restrict__ dst,
                           int nsrc, int ndst) {
  const int i = blockIdx.x * blockDim.x + threadIdx.x;
  if (i < ndst) dst[i] = (i < nsrc) ? src[i] : 0.0f;
}

// ---------------------------------------------------------------------------
// pointwise LSTM: preacts f16 [8192, 4096] interleaved (f,i,s,o per j)
// ---------------------------------------------------------------------------
__global__ void lstm_pointwise(const half_t* __restrict__ pre, const float* __restrict__ c,
                               float* __restrict__ hout, half_t* __restrict__ h2) {
  const size_t idx = (size_t)blockIdx.x * blockDim.x + threadIdx.x;  // b*1024+j
  const half4v p = *(const half4v*)(pre + idx * 4);
  const float f = sigmoidf_((float)p.x);
  const float i = sigmoidf_((float)p.y);
  const float s = tanhf((float)p.z);
  const float o = sigmoidf_((float)p.w);
  const float cn = c[idx] * f + i * s;
  const float hn = o * tanhf(cn);
  hout[idx] = hn;
  h2[idx] = (half_t)hn;
}

// ---------------------------------------------------------------------------
// softmax over rows of 512: one wave per row, 4 rows per 256-thread block
// ---------------------------------------------------------------------------
__global__ __launch_bounds__(256) void softmax512(const float* __restrict__ logits,
                                                  float* __restrict__ out) {
  const int row = blockIdx.x * 4 + (threadIdx.x >> 6);
  const int lane = threadIdx.x & 63;
  const float4v* src = (const float4v*)(logits + (size_t)row * 512);
  const float4v v0 = src[lane * 2];
  const float4v v1 = src[lane * 2 + 1];
  float mx = fmaxf(fmaxf(fmaxf(v0.x, v0.y), fmaxf(v0.z, v0.w)),
                   fmaxf(fmaxf(v1.x, v1.y), fmaxf(v1.z, v1.w)));
#pragma unroll
  for (int off = 32; off > 0; off >>= 1) mx = fmaxf(mx, __shfl_xor(mx, off, 64));
  const float e0 = __expf(v0.x - mx), e1 = __expf(v0.y - mx);
  const float e2 = __expf(v0.z - mx), e3 = __expf(v0.w - mx);
  const float e4 = __expf(v1.x - mx), e5 = __expf(v1.y - mx);
  const float e6 = __expf(v1.z - mx), e7 = __expf(v1.w - mx);
  float sum = ((e0 + e1) + (e2 + e3)) + ((e4 + e5) + (e6 + e7));
#pragma unroll
  for (int off = 32; off > 0; off >>= 1) sum += __shfl_xor(sum, off, 64);
  const float inv = 1.0f / sum;
  float4v o0, o1;
  o0.x = e0 * inv; o0.y = e1 * inv; o0.z = e2 * inv; o0.w = e3 * inv;
  o1.x = e4 * inv; o1.y = e5 * inv; o1.z = e6 * inv; o1.w = e7 * inv;
  float4v* dst = (float4v*)(out + (size_t)row * 512);
  dst[lane * 2] = o0;
  dst[lane * 2 + 1] = o1;
}

// ---------------------------------------------------------------------------
extern "C" void kernel_launch(void* const* d_in, const int* in_sizes, int n_in,
                              void* d_out, int out_size, void* d_ws, size_t ws_size,
                              hipStream_t stream) {
  const float* x = (const float*)d_in[0];
  const float* h = (const float*)d_in[1];
  const float* c = (const float*)d_in[2];
  const float* Wfi = (const float*)d_in[3];  const float* bfi = (const float*)d_in[4];
  const float* Wfh = (const float*)d_in[5];  const float* bfh = (const float*)d_in[6];
  const float* Wii = (const float*)d_in[7];  const float* bii = (const float*)d_in[8];
  const float* Wih = (const float*)d_in[9];  const float* bih = (const float*)d_in[10];
  const float* Wsi = (const float*)d_in[11]; const float* bsi = (const float*)d_in[12];
  const float* Wsh = (const float*)d_in[13]; const float* bsh = (const float*)d_in[14];
  const float* Woi = (const float*)d_in[15]; const float* boi = (const float*)d_in[16];
  const float* Woh = (const float*)d_in[17]; const float* boh = (const float*)d_in[18];
  const float* Wd1 = (const float*)d_in[19]; const float* bd1 = (const float*)d_in[20];
  const float* Wd2 = (const float*)d_in[21]; const float* bd2 = (const float*)d_in[22];
  const float* Wd3 = (const float*)d_in[23]; const float* bd3 = (const float*)d_in[24];

  char* ws = (char*)d_ws;
  size_t o = 0;
  auto alloc = [&](size_t bytes) {
    size_t cur = o;
    o += (bytes + 255) & ~(size_t)255;
    return cur;
  };
  half_t* XH   = (half_t*)(ws + alloc((size_t)8192 * 2048 * 2));  // 33.5 MB
  half_t* WALL = (half_t*)(ws + alloc((size_t)4096 * 2048 * 2));  // 16.8 MB
  float*  BALL = (float*)(ws + alloc(4096 * 4));
  half_t* WD1  = (half_t*)(ws + alloc((size_t)512 * 1024 * 2));
  half_t* WD2  = (half_t*)(ws + alloc((size_t)384 * 512 * 2));
  float*  BD2  = (float*)(ws + alloc(384 * 4));
  half_t* WD3  = (half_t*)(ws + alloc((size_t)512 * 384 * 2));
  half_t* H2   = (half_t*)(ws + alloc((size_t)8192 * 1024 * 2));  // 16.8 MB
  half_t* D1   = (half_t*)(ws + alloc((size_t)8192 * 512 * 2));   // 8.4 MB
  half_t* D2   = (half_t*)(ws + alloc((size_t)8192 * 384 * 2));   // 6.3 MB
  half_t* PRE  = (half_t*)(ws + alloc((size_t)8192 * 4096 * 2));  // 67 MB
  float*  LOG  = (float*)XH;  // alias: XH dead after gates GEMM  (total ~151 MB)

  float* h_out = (float*)d_out;                          // [8192,1024]
  float* d_outp = (float*)d_out + (size_t)8192 * 1024;   // [8192,512]

  // --- prep (inputs re-poisoned each call, so convert every launch) ---
  pack_xh<<<16384, 256, 0, stream>>>(x, h, XH);
  pack_wall<<<8192, 256, 0, stream>>>(Wfi, Wfh, Wii, Wih, Wsi, Wsh, Woi, Woh, WALL);
  bias_all<<<16, 256, 0, stream>>>(bfi, bfh, bii, bih, bsi, bsh, boi, boh, BALL);
  conv_pad<<<2048, 256, 0, stream>>>(Wd1, WD1, 512, 1024, 1024, 512 * 1024);
  conv_pad<<<768, 256, 0, stream>>>(Wd2, WD2, 341, 512, 512, 384 * 512);
  pad_bias_k<<<2, 256, 0, stream>>>(bd2, BD2, 341, 384);
  conv_pad<<<768, 256, 0, stream>>>(Wd3, WD3, 512, 341, 384, 512 * 384);

  // --- gates: [8192,2048] @ [4096,2048]^T + ball -> PRE f16 ---
  gemm_f16<0, 1><<<dim3(32, 64), 256, 0, stream>>>(XH, WALL, BALL, PRE, 4096, 2048);
  // --- LSTM pointwise -> h_out (f32) + H2 (f16) ---
  lstm_pointwise<<<32768, 256, 0, stream>>>(PRE, c, h_out, H2);
  // --- decoder ---
  gemm_f16<1, 1><<<dim3(4, 64), 256, 0, stream>>>(H2, WD1, bd1, D1, 512, 1024);
  gemm_f16<1, 1><<<dim3(3, 64), 256, 0, stream>>>(D1, WD2, BD2, D2, 384, 512);
  gemm_f16<0, 0><<<dim3(4, 64), 256, 0, stream>>>(D2, WD3, bd3, LOG, 512, 384);
  softmax512<<<2048, 256, 0, stream>>>(LOG, d_outp);
}

// Round 2
// 446.186 us; speedup vs baseline: 1.1199x; 1.1199x over previous
//
#include <hip/hip_runtime.h>
#include <cstdint>
#include <cstddef>

// ---------------------------------------------------------------------------
// LSTM cell + 3-layer decoder, MI355X (gfx950)
// B=8192, H=1024, D_IN=1024, D1=512, D2=341(pad 384), A=512
// R2: LSTM pointwise fused into gates-GEMM epilogue (gate index lives in the
// MFMA j-fragment: WALL row n -> gate g=(n>>4)&3, unit u=((n>>6)<<4)|(n&15)).
// Prep fused 7->2 kernels. Decoder GEMMs use TM=64 tiles (2 blocks/CU).
// ---------------------------------------------------------------------------

typedef _Float16 half_t;
typedef _Float16 half8 __attribute__((ext_vector_type(8)));
typedef _Float16 half4v __attribute__((ext_vector_type(4)));
typedef float float4v __attribute__((ext_vector_type(4)));

#define GLD_LDS16(gptr, lptr)                                                  \
  __builtin_amdgcn_global_load_lds(                                            \
      (const __attribute__((address_space(1))) void*)(gptr),                   \
      (__attribute__((address_space(3))) void*)(lptr), 16, 0, 0)

__device__ __forceinline__ float fsig(float x) {
  return 1.0f / (1.0f + __expf(-x));
}
__device__ __forceinline__ float ftanh_(float x) {
  // tanh(x) = 1 - 2/(exp(2x)+1); exact at +-inf, ~1e-7 rel err elsewhere
  const float e = __expf(2.0f * x);
  return 1.0f - 2.0f / (e + 1.0f);
}

// ---------------------------------------------------------------------------
// Generic GEMM: C[M,N] = A[M,K] @ Bw[N,K]^T + bias[N]; optional tanh; f16/f32 out
// TM in {128, 64}; TN fixed 128; BK=32; 256 threads.
//   TM=128: waves 2x2, each 64x64 (acc 4x4)
//   TM=64 : waves 1x4, each 64x32 (acc 4x2) -- for small-N latency-bound GEMMs
// ---------------------------------------------------------------------------
template <int TM, int ACT_TANH, int HALF_OUT>
__global__ __launch_bounds__(256) void gemm_f16(const half_t* __restrict__ A,
                                                const half_t* __restrict__ Bw,
                                                const float* __restrict__ bias,
                                                void* __restrict__ Cp,
                                                int N, int K) {
  constexpr int ASZ = TM * 64;                 // A-tile bytes
  constexpr int NPASS = (ASZ + 8192) / 4096;   // staging passes (4KB per pass)
  constexpr int JW = (TM == 128) ? 4 : 2;      // 16-col MFMA tiles per wave
  __shared__ alignas(16) half_t As[TM * 32];
  __shared__ alignas(16) half_t Bs[128 * 32];
  const int tid = threadIdx.x;
  const int lane = tid & 63;
  const int wave = tid >> 6;
  const size_t tile_m = (size_t)blockIdx.y * TM;
  const size_t tile_n = (size_t)blockIdx.x * 128;
  const int wm = (TM == 128) ? (wave >> 1) * 64 : 0;
  const int wn = (TM == 128) ? (wave & 1) * 64 : wave * 32;

  const half_t* gp[NPASS];
  half_t* lbase[NPASS];
  int lofs[NPASS];
#pragma unroll
  for (int s = 0; s < NPASS; ++s) {
    const int p = s * 4096 + tid * 16;
    if (p < ASZ) {
      const int r = p >> 6, cc = (p & 63) >> 1;
      gp[s] = A + (tile_m + r) * (size_t)K + cc;
      lbase[s] = As; lofs[s] = p;
    } else {
      const int q = p - ASZ;
      const int r = q >> 6, cc = (q & 63) >> 1;
      gp[s] = Bw + (tile_n + r) * (size_t)K + cc;
      lbase[s] = Bs; lofs[s] = q;
    }
  }

  float4v acc[4][JW] = {};
  for (int k0 = 0; k0 < K; k0 += 32) {
    __syncthreads();
#pragma unroll
    for (int s = 0; s < NPASS; ++s) GLD_LDS16(gp[s] + k0, (char*)lbase[s] + lofs[s]);
    __syncthreads();
    const int kh = (lane >> 4) * 8;
    half8 af[4], bf[JW];
#pragma unroll
    for (int i = 0; i < 4; ++i)
      af[i] = *(const half8*)(As + (wm + i * 16 + (lane & 15)) * 32 + kh);
#pragma unroll
    for (int j = 0; j < JW; ++j)
      bf[j] = *(const half8*)(Bs + (wn + j * 16 + (lane & 15)) * 32 + kh);
#pragma unroll
    for (int i = 0; i < 4; ++i)
#pragma unroll
      for (int j = 0; j < JW; ++j)
        acc[i][j] =
            __builtin_amdgcn_mfma_f32_16x16x32_f16(af[i], bf[j], acc[i][j], 0, 0, 0);
  }

  // epilogue: C/D layout col=lane&15 (n), row=(lane>>4)*4+reg (m)  [m89-verified]
  const size_t mb = tile_m + wm + ((lane >> 4) << 2);
  const size_t nb = tile_n + wn + (lane & 15);
#pragma unroll
  for (int j = 0; j < JW; ++j) {
    const size_t n = nb + j * 16;
    const float bv = bias[n];
#pragma unroll
    for (int i = 0; i < 4; ++i) {
#pragma unroll
      for (int r = 0; r < 4; ++r) {
        float v = acc[i][j][r] + bv;
        if (ACT_TANH) v = ftanh_(v);
        const size_t off = (mb + i * 16 + r) * (size_t)N + n;
        if (HALF_OUT)
          ((half_t*)Cp)[off] = (half_t)v;
        else
          ((float*)Cp)[off] = v;
      }
    }
  }
}

// ---------------------------------------------------------------------------
// Gates GEMM with fused LSTM epilogue.
// A=XH [8192,2048], Bw=WALL [4096,2048], bias=BALL[4096], c [8192,1024].
// Column n: gate g=(n>>4)&3 == j-fragment index; unit u=((n>>6)<<4)|(n&15).
// Each lane holds acc[i][g][r] = preact(row, u, gate g) -> LSTM in-register.
// ---------------------------------------------------------------------------
__global__ __launch_bounds__(256) void gemm_gates(const half_t* __restrict__ A,
                                                  const half_t* __restrict__ Bw,
                                                  const float* __restrict__ bias,
                                                  const float* __restrict__ cin,
                                                  float* __restrict__ hout,
                                                  half_t* __restrict__ h2) {
  constexpr int K = 2048;
  __shared__ alignas(16) half_t As[128 * 32];
  __shared__ alignas(16) half_t Bs[128 * 32];
  const int tid = threadIdx.x;
  const int lane = tid & 63;
  const int wave = tid >> 6;
  const size_t tile_m = (size_t)blockIdx.y * 128;
  const size_t tile_n = (size_t)blockIdx.x * 128;
  const int wm = (wave >> 1) * 64;
  const int wn = (wave & 1) * 64;

  const int p0 = tid * 16;
  const int p1 = 4096 + tid * 16;
  const int r0 = p0 >> 6, c0 = (p0 & 63) >> 1;
  const int r1 = p1 >> 6, c1 = (p1 & 63) >> 1;
  const half_t* Ag0 = A + (tile_m + r0) * (size_t)K + c0;
  const half_t* Ag1 = A + (tile_m + r1) * (size_t)K + c1;
  const half_t* Bg0 = Bw + (tile_n + r0) * (size_t)K + c0;
  const half_t* Bg1 = Bw + (tile_n + r1) * (size_t)K + c1;

  float4v acc[4][4] = {};
  for (int k0 = 0; k0 < K; k0 += 32) {
    __syncthreads();
    GLD_LDS16(Ag0 + k0, (char*)As + p0);
    GLD_LDS16(Ag1 + k0, (char*)As + p1);
    GLD_LDS16(Bg0 + k0, (char*)Bs + p0);
    GLD_LDS16(Bg1 + k0, (char*)Bs + p1);
    __syncthreads();
    const int kh = (lane >> 4) * 8;
    half8 af[4], bf[4];
#pragma unroll
    for (int i = 0; i < 4; ++i)
      af[i] = *(const half8*)(As + (wm + i * 16 + (lane & 15)) * 32 + kh);
#pragma unroll
    for (int j = 0; j < 4; ++j)
      bf[j] = *(const half8*)(Bs + (wn + j * 16 + (lane & 15)) * 32 + kh);
#pragma unroll
    for (int i = 0; i < 4; ++i)
#pragma unroll
      for (int j = 0; j < 4; ++j)
        acc[i][j] =
            __builtin_amdgcn_mfma_f32_16x16x32_f16(af[i], bf[j], acc[i][j], 0, 0, 0);
  }

  // fused LSTM epilogue
  const int l = lane & 15;
  const int quad = lane >> 4;
  const int nwave = (int)tile_n + wn;             // multiple of 64
  const size_t u = (size_t)((nwave >> 6) << 4) + l;  // hidden unit index
  float bg[4];
#pragma unroll
  for (int g = 0; g < 4; ++g) bg[g] = bias[nwave + g * 16 + l];
#pragma unroll
  for (int i = 0; i < 4; ++i) {
#pragma unroll
    for (int r = 0; r < 4; ++r) {
      const size_t row = tile_m + wm + quad * 4 + i * 16 + r;
      const size_t off = row * 1024 + u;
      const float F = fsig(acc[i][0][r] + bg[0]);
      const float I = fsig(acc[i][1][r] + bg[1]);
      const float S = ftanh_(acc[i][2][r] + bg[2]);
      const float O = fsig(acc[i][3][r] + bg[3]);
      const float cn = cin[off] * F + I * S;
      const float hn = O * ftanh_(cn);
      hout[off] = hn;
      h2[off] = (half_t)hn;
    }
  }
}

// ---------------------------------------------------------------------------
// prep_pack: blocks [0,16384) -> XH f16 [8192,2048]; [16384,24576) -> WALL.
// WALL row n: g=(n>>4)&3, u=((n>>6)<<4)|(n&15); cols 0..1023=W_gi[u], rest=W_gh[u]
// ---------------------------------------------------------------------------
__global__ void prep_pack(const float* __restrict__ x, const float* __restrict__ h,
                          const float* __restrict__ Wfi, const float* __restrict__ Wfh,
                          const float* __restrict__ Wii, const float* __restrict__ Wih,
                          const float* __restrict__ Wsi, const float* __restrict__ Wsh,
                          const float* __restrict__ Woi, const float* __restrict__ Woh,
                          half_t* __restrict__ xh, half_t* __restrict__ wall) {
  const int bid = blockIdx.x;
  const float* src;
  half_t* dst;
  size_t idx;
  if (bid < 16384) {
    idx = ((size_t)bid * 256 + threadIdx.x) * 4;
    const size_t b = idx >> 11;
    const int col = (int)(idx & 2047);
    src = (col < 1024) ? (x + b * 1024 + col) : (h + b * 1024 + (col - 1024));
    dst = xh + idx;
  } else {
    idx = ((size_t)(bid - 16384) * 256 + threadIdx.x) * 4;
    const int n = (int)(idx >> 11);
    const int col = (int)(idx & 2047);
    const int g = (n >> 4) & 3;
    const size_t u = (size_t)(((n >> 6) << 4) | (n & 15));
    const float* Wi = (g == 0) ? Wfi : (g == 1) ? Wii : (g == 2) ? Wsi : Woi;
    const float* Wh = (g == 0) ? Wfh : (g == 1) ? Wih : (g == 2) ? Wsh : Woh;
    src = (col < 1024) ? (Wi + u * 1024 + col) : (Wh + u * 1024 + (col - 1024));
    dst = wall + idx;
  }
  const float4v v = *(const float4v*)src;
  half4v o;
  o.x = (half_t)v.x; o.y = (half_t)v.y; o.z = (half_t)v.z; o.w = (half_t)v.w;
  *(half4v*)dst = o;
}

// ---------------------------------------------------------------------------
// prep_small: WD1 [0,512) | WD2 [512,704) | WD3 [704,896) | BALL [896,912) |
//             BD2 [912,914)      (914 blocks x 256 threads)
// ---------------------------------------------------------------------------
__global__ void prep_small(const float* __restrict__ Wd1, const float* __restrict__ Wd2,
                           const float* __restrict__ Wd3, const float* __restrict__ bd2,
                           const float* __restrict__ bfi, const float* __restrict__ bfh,
                           const float* __restrict__ bii, const float* __restrict__ bih,
                           const float* __restrict__ bsi, const float* __restrict__ bsh,
                           const float* __restrict__ boi, const float* __restrict__ boh,
                           half_t* __restrict__ WD1, half_t* __restrict__ WD2h,
                           half_t* __restrict__ WD3h, float* __restrict__ BALL,
                           float* __restrict__ BD2) {
  const int bid = blockIdx.x;
  const int tid = threadIdx.x;
  if (bid < 512) {  // WD1: [512,1024] f32 -> f16, no padding
    const size_t i4 = ((size_t)bid * 256 + tid) * 4;
    const float4v v = *(const float4v*)(Wd1 + i4);
    half4v o;
    o.x = (half_t)v.x; o.y = (half_t)v.y; o.z = (half_t)v.z; o.w = (half_t)v.w;
    *(half4v*)(WD1 + i4) = o;
  } else if (bid < 704) {  // WD2: [341,512] -> [384,512], row-padded
    const size_t i4 = ((size_t)(bid - 512) * 256 + tid) * 4;
    const int r = (int)(i4 >> 9);
    const int cc = (int)(i4 & 511);
    half4v o;
    if (r < 341) {
      const float4v v = *(const float4v*)(Wd2 + (size_t)r * 512 + cc);
      o.x = (half_t)v.x; o.y = (half_t)v.y; o.z = (half_t)v.z; o.w = (half_t)v.w;
    } else {
      o.x = (half_t)0.f; o.y = (half_t)0.f; o.z = (half_t)0.f; o.w = (half_t)0.f;
    }
    *(half4v*)(WD2h + i4) = o;
  } else if (bid < 896) {  // WD3: [512,341] -> [512,384], col-padded
    const size_t i4 = ((size_t)(bid - 704) * 256 + tid) * 4;
    const int r = (int)(i4 / 384);
    const int cc = (int)(i4 - (size_t)r * 384);
    half4v o;
    o.x = (cc + 0 < 341) ? (half_t)Wd3[(size_t)r * 341 + cc + 0] : (half_t)0.f;
    o.y = (cc + 1 < 341) ? (half_t)Wd3[(size_t)r * 341 + cc + 1] : (half_t)0.f;
    o.z = (cc + 2 < 341) ? (half_t)Wd3[(size_t)r * 341 + cc + 2] : (half_t)0.f;
    o.w = (cc + 3 < 341) ? (half_t)Wd3[(size_t)r * 341 + cc + 3] : (half_t)0.f;
    *(half4v*)(WD3h + i4) = o;
  } else if (bid < 912) {  // BALL[4096], WALL row ordering
    const int n = (bid - 896) * 256 + tid;
    const int g = (n >> 4) & 3;
    const int u = ((n >> 6) << 4) | (n & 15);
    const float* bi = (g == 0) ? bfi : (g == 1) ? bii : (g == 2) ? bsi : boi;
    const float* bh = (g == 0) ? bfh : (g == 1) ? bih : (g == 2) ? bsh : boh;
    BALL[n] = bi[u] + bh[u];
  } else {  // BD2[384]
    const int i = (bid - 912) * 256 + tid;
    if (i < 384) BD2[i] = (i < 341) ? bd2[i] : 0.0f;
  }
}

// ---------------------------------------------------------------------------
// softmax over rows of 512: one wave per row, 4 rows per block
// ---------------------------------------------------------------------------
__global__ __launch_bounds__(256) void softmax512(const float* __restrict__ logits,
                                                  float* __restrict__ out) {
  const int row = blockIdx.x * 4 + (threadIdx.x >> 6);
  const int lane = threadIdx.x & 63;
  const float4v* src = (const float4v*)(logits + (size_t)row * 512);
  const float4v v0 = src[lane * 2];
  const float4v v1 = src[lane * 2 + 1];
  float mx = fmaxf(fmaxf(fmaxf(v0.x, v0.y), fmaxf(v0.z, v0.w)),
                   fmaxf(fmaxf(v1.x, v1.y), fmaxf(v1.z, v1.w)));
#pragma unroll
  for (int off = 32; off > 0; off >>= 1) mx = fmaxf(mx, __shfl_xor(mx, off, 64));
  const float e0 = __expf(v0.x - mx), e1 = __expf(v0.y - mx);
  const float e2 = __expf(v0.z - mx), e3 = __expf(v0.w - mx);
  const float e4 = __expf(v1.x - mx), e5 = __expf(v1.y - mx);
  const float e6 = __expf(v1.z - mx), e7 = __expf(v1.w - mx);
  float sum = ((e0 + e1) + (e2 + e3)) + ((e4 + e5) + (e6 + e7));
#pragma unroll
  for (int off = 32; off > 0; off >>= 1) sum += __shfl_xor(sum, off, 64);
  const float inv = 1.0f / sum;
  float4v o0, o1;
  o0.x = e0 * inv; o0.y = e1 * inv; o0.z = e2 * inv; o0.w = e3 * inv;
  o1.x = e4 * inv; o1.y = e5 * inv; o1.z = e6 * inv; o1.w = e7 * inv;
  float4v* dst = (float4v*)(out + (size_t)row * 512);
  dst[lane * 2] = o0;
  dst[lane * 2 + 1] = o1;
}

// ---------------------------------------------------------------------------
extern "C" void kernel_launch(void* const* d_in, const int* in_sizes, int n_in,
                              void* d_out, int out_size, void* d_ws, size_t ws_size,
                              hipStream_t stream) {
  const float* x = (const float*)d_in[0];
  const float* h = (const float*)d_in[1];
  const float* c = (const float*)d_in[2];
  const float* Wfi = (const float*)d_in[3];  const float* bfi = (const float*)d_in[4];
  const float* Wfh = (const float*)d_in[5];  const float* bfh = (const float*)d_in[6];
  const float* Wii = (const float*)d_in[7];  const float* bii = (const float*)d_in[8];
  const float* Wih = (const float*)d_in[9];  const float* bih = (const float*)d_in[10];
  const float* Wsi = (const float*)d_in[11]; const float* bsi = (const float*)d_in[12];
  const float* Wsh = (const float*)d_in[13]; const float* bsh = (const float*)d_in[14];
  const float* Woi = (const float*)d_in[15]; const float* boi = (const float*)d_in[16];
  const float* Woh = (const float*)d_in[17]; const float* boh = (const float*)d_in[18];
  const float* Wd1 = (const float*)d_in[19]; const float* bd1 = (const float*)d_in[20];
  const float* Wd2 = (const float*)d_in[21]; const float* bd2 = (const float*)d_in[22];
  const float* Wd3 = (const float*)d_in[23]; const float* bd3 = (const float*)d_in[24];

  char* ws = (char*)d_ws;
  size_t o = 0;
  auto alloc = [&](size_t bytes) {
    size_t cur = o;
    o += (bytes + 255) & ~(size_t)255;
    return cur;
  };
  half_t* XH   = (half_t*)(ws + alloc((size_t)8192 * 2048 * 2));  // 33.5 MB
  half_t* WALL = (half_t*)(ws + alloc((size_t)4096 * 2048 * 2));  // 16.8 MB
  float*  BALL = (float*)(ws + alloc(4096 * 4));
  half_t* WD1  = (half_t*)(ws + alloc((size_t)512 * 1024 * 2));
  half_t* WD2  = (half_t*)(ws + alloc((size_t)384 * 512 * 2));
  float*  BD2  = (float*)(ws + alloc(384 * 4));
  half_t* WD3  = (half_t*)(ws + alloc((size_t)512 * 384 * 2));
  half_t* H2   = (half_t*)(ws + alloc((size_t)8192 * 1024 * 2));  // 16.8 MB
  half_t* D1   = (half_t*)(ws + alloc((size_t)8192 * 512 * 2));   // 8.4 MB
  half_t* D2   = (half_t*)(ws + alloc((size_t)8192 * 384 * 2));   // 6.3 MB
  float*  LOG  = (float*)XH;  // alias: XH dead after gates GEMM  (~84 MB total)

  float* h_out = (float*)d_out;                          // [8192,1024] f32
  float* d_outp = (float*)d_out + (size_t)8192 * 1024;   // [8192,512] f32

  // prep: 2 launches (inputs re-poisoned every call, so convert every call)
  prep_pack<<<24576, 256, 0, stream>>>(x, h, Wfi, Wfh, Wii, Wih, Wsi, Wsh, Woi, Woh,
                                       XH, WALL);
  prep_small<<<914, 256, 0, stream>>>(Wd1, Wd2, Wd3, bd2, bfi, bfh, bii, bih, bsi, bsh,
                                      boi, boh, WD1, WD2, WD3, BALL, BD2);

  // gates GEMM + fused LSTM -> h_out (f32) + H2 (f16)
  gemm_gates<<<dim3(32, 64), 256, 0, stream>>>(XH, WALL, BALL, c, h_out, H2);

  // decoder (TM=64 tiles: 512/384/512 blocks)
  gemm_f16<64, 1, 1><<<dim3(4, 128), 256, 0, stream>>>(H2, WD1, bd1, D1, 512, 1024);
  gemm_f16<64, 1, 1><<<dim3(3, 128), 256, 0, stream>>>(D1, WD2, BD2, D2, 384, 512);
  gemm_f16<64, 0, 0><<<dim3(4, 128), 256, 0, stream>>>(D2, WD3, bd3, LOG, 512, 384);
  softmax512<<<2048, 256, 0, stream>>>(LOG, d_outp);
}